// Round 2
// baseline (297.951 us; speedup 1.0000x reference)
//
#include <hip/hip_runtime.h>

#define B_ 32
#define T_ 512
#define D_ 512
#define MAXF_ 4096

typedef float f4 __attribute__((ext_vector_type(4)));

// Stage 1: per-batch inclusive scan of durations in LDS, then direct scatter
// idx_map[start..end) = t (<=7 stores/thread) and -1 fill for masked tail.
__global__ __launch_bounds__(512) void lr_prep_kernel(const int* __restrict__ dur,
                                                      int* __restrict__ idx_map,
                                                      float* __restrict__ mel_out) {
    __shared__ int s[T_];
    const int b = blockIdx.x;
    const int t = threadIdx.x;
    const int d = dur[b * T_ + t];
    s[t] = d;
    __syncthreads();
    #pragma unroll
    for (int off = 1; off < T_; off <<= 1) {
        int tmp = (t >= off) ? s[t - off] : 0;
        __syncthreads();
        s[t] += tmp;
        __syncthreads();
    }
    const int end = s[t];
    const int start = end - d;
    const int total = s[T_ - 1];
    if (t == T_ - 1) {
        mel_out[b] = (float)(total > 1 ? total : 1);
    }
    int* __restrict__ im = idx_map + b * MAXF_;
    for (int p = start; p < end; ++p) im[p] = t;          // duration <= 7
    for (int p = total + t; p < MAXF_; p += T_) im[p] = -1;
}

// Stage 2: streaming gather, 16 frames (32 KB of output) per block.
//  - idx for the block's 16 frames staged in LDS once (16 dword loads/block).
//  - BRANCHLESS inner loop: clamp idx to 0, unconditional load (masked frames
//    read the batch's row 0 -> L1-hot), v_cndmask the zeros in. This lets the
//    compiler issue all 8 independent x-loads back-to-back (one vmcnt drain)
//    instead of 8 serialized load->wait->store chains behind s_cbranch.
//  - XCD-chunked block swizzle: hardware round-robins blockIdx across the 8
//    XCD L2s; remap so each XCD owns 1024 consecutive chunks (= 4 whole
//    batches, 4 MB of x) instead of all 8 XCDs pulling all 32 MB of x.
#define FPB_ 16
__global__ __launch_bounds__(256) void lr_gather_kernel(const f4* __restrict__ x,
                                                        const int* __restrict__ idx_map,
                                                        f4* __restrict__ out) {
    __shared__ int s_idx[FPB_];
    const int tid = threadIdx.x;
    // bijective XCD swizzle: 8192 blocks, 8 XCDs, 1024 chunks per XCD
    const int bid = ((blockIdx.x & 7) << 10) + (blockIdx.x >> 3);
    const int f0 = bid * FPB_;                   // first global frame of chunk
    if (tid < FPB_) s_idx[tid] = idx_map[f0 + tid];
    __syncthreads();
    const int b = bid >> 8;                      // 256 chunks per batch
    const f4* __restrict__ xb = x + ((size_t)(b * T_) << 7);
    const int c = tid & 127;                     // f4 column within frame
    const size_t base = ((size_t)f0 << 7) + tid; // first f4 this thread stores
    #pragma unroll
    for (int k = 0; k < 8; ++k) {
        const int fl = (tid >> 7) + 2 * k;       // local frame index 0..15
        const int idx = s_idx[fl];               // wave-uniform
        const int cidx = idx < 0 ? 0 : idx;      // clamp: masked -> row 0 (L1-hot)
        f4 v = xb[((size_t)cidx << 7) + c];
        if (idx < 0) v = (f4){0.f, 0.f, 0.f, 0.f};   // -> 4x v_cndmask, no branch
        __builtin_nontemporal_store(v, &out[base + (size_t)k * 256]);
    }
}

extern "C" void kernel_launch(void* const* d_in, const int* in_sizes, int n_in,
                              void* d_out, int out_size, void* d_ws, size_t ws_size,
                              hipStream_t stream) {
    const float* x = (const float*)d_in[0];
    const int* durations = (const int*)d_in[1];
    float* out = (float*)d_out;
    float* mel_out = out + (size_t)B_ * MAXF_ * D_;
    int* idx_map = (int*)d_ws;  // B_*MAXF_ ints = 512 KB

    lr_prep_kernel<<<B_, T_, 0, stream>>>(durations, idx_map, mel_out);

    const size_t n_vec4 = (size_t)B_ * MAXF_ * (D_ / 4);  // 16,777,216
    lr_gather_kernel<<<(int)(n_vec4 / (FPB_ * (D_ / 4))), 256, 0, stream>>>(
        (const f4*)x, idx_map, (f4*)out);
}

// Round 3
// 292.782 us; speedup vs baseline: 1.0177x; 1.0177x over previous
//
#include <hip/hip_runtime.h>

#define B_ 32
#define T_ 512
#define D_ 512
#define MAXF_ 4096

typedef float f4 __attribute__((ext_vector_type(4)));

// Stage 1: per-batch inclusive scan of durations, then direct scatter
// idx_map[start..end) = t (<=7 stores/thread) and -1 fill for masked tail.
// Scan = per-wave shfl_up scan (no barriers) + one LDS step for the 8 wave
// sums: 1 __syncthreads total (was 18). 32 blocks -> latency matters.
__global__ __launch_bounds__(512) void lr_prep_kernel(const int* __restrict__ dur,
                                                      int* __restrict__ idx_map,
                                                      float* __restrict__ mel_out) {
    __shared__ int wsum[8];
    const int b = blockIdx.x;
    const int t = threadIdx.x;
    const int lane = t & 63;
    const int wave = t >> 6;
    const int d = dur[b * T_ + t];
    int v = d;                                   // inclusive scan within wave
    #pragma unroll
    for (int off = 1; off < 64; off <<= 1) {
        int u = __shfl_up(v, off, 64);
        if (lane >= off) v += u;
    }
    if (lane == 63) wsum[wave] = v;
    __syncthreads();
    int woff = 0, total = 0;
    #pragma unroll
    for (int w = 0; w < 8; ++w) {                // LDS broadcast reads, cheap
        const int s = wsum[w];
        woff  += (w < wave) ? s : 0;
        total += s;
    }
    const int end = v + woff;
    const int start = end - d;
    if (t == 0) mel_out[b] = (float)(total > 1 ? total : 1);
    int* __restrict__ im = idx_map + b * MAXF_;
    for (int p = start; p < end; ++p) im[p] = t;          // duration <= 7
    for (int p = total + t; p < MAXF_; p += T_) im[p] = -1;
}

// Stage 2: streaming gather, 16 frames (32 KB of output) per block.
// Identical structure to round 2 EXCEPT the store: plain (write-back) stores
// instead of nontemporal. The harness's own 1 GiB fills hit 6.36 TB/s with
// plain stores; this A/Bs whether gfx950 nt stores were capping the stream.
#define FPB_ 16
__global__ __launch_bounds__(256) void lr_gather_kernel(const f4* __restrict__ x,
                                                        const int* __restrict__ idx_map,
                                                        f4* __restrict__ out) {
    __shared__ int s_idx[FPB_];
    const int tid = threadIdx.x;
    // bijective XCD swizzle: 8192 blocks, 8 XCDs, 1024 chunks per XCD
    const int bid = ((blockIdx.x & 7) << 10) + (blockIdx.x >> 3);
    const int f0 = bid * FPB_;                   // first global frame of chunk
    if (tid < FPB_) s_idx[tid] = idx_map[f0 + tid];
    __syncthreads();
    const int b = bid >> 8;                      // 256 chunks per batch
    const f4* __restrict__ xb = x + ((size_t)(b * T_) << 7);
    const int c = tid & 127;                     // f4 column within frame
    const size_t base = ((size_t)f0 << 7) + tid; // first f4 this thread stores
    #pragma unroll
    for (int k = 0; k < 8; ++k) {
        const int fl = (tid >> 7) + 2 * k;       // local frame index 0..15
        const int idx = s_idx[fl];               // wave-uniform LDS broadcast
        const int cidx = idx < 0 ? 0 : idx;      // clamp: masked -> row 0 (L1-hot)
        f4 v = xb[((size_t)cidx << 7) + c];
        if (idx < 0) v = (f4){0.f, 0.f, 0.f, 0.f};   // 4x v_cndmask, no branch
        out[base + (size_t)k * 256] = v;         // PLAIN store (A/B vs nt)
    }
}

extern "C" void kernel_launch(void* const* d_in, const int* in_sizes, int n_in,
                              void* d_out, int out_size, void* d_ws, size_t ws_size,
                              hipStream_t stream) {
    const float* x = (const float*)d_in[0];
    const int* durations = (const int*)d_in[1];
    float* out = (float*)d_out;
    float* mel_out = out + (size_t)B_ * MAXF_ * D_;
    int* idx_map = (int*)d_ws;  // B_*MAXF_ ints = 512 KB

    lr_prep_kernel<<<B_, T_, 0, stream>>>(durations, idx_map, mel_out);

    const size_t n_vec4 = (size_t)B_ * MAXF_ * (D_ / 4);  // 16,777,216
    lr_gather_kernel<<<(int)(n_vec4 / (FPB_ * (D_ / 4))), 256, 0, stream>>>(
        (const f4*)x, idx_map, (f4*)out);
}

// Round 4
// 291.964 us; speedup vs baseline: 1.0205x; 1.0028x over previous
//
#include <hip/hip_runtime.h>

#define B_ 32
#define T_ 512
#define D_ 512
#define MAXF_ 4096
#define FPB_ 32                     // frames per block
#define NBLK_ (B_ * MAXF_ / FPB_)   // 4096 blocks
#define CPB_ (MAXF_ / FPB_)         // 128 chunks per batch

typedef float f4 __attribute__((ext_vector_type(4)));

// Single fused kernel: each block owns 32 output frames of one batch.
//  1. Re-derive the batch's duration inclusive scan locally: 256 threads load
//     2 durations each (coalesced int2), shfl_up wave scan of pair-sums + 4
//     wave partials via LDS. Cost ~0.25 us/block; deletes the 32-block prep
//     kernel (only 32 CUs active there), its launch gap, and the idx_map
//     global round-trip. Workspace now entirely unused.
//  2. Scatter coverage [start_t, end_t) clipped to this block's frame window
//     into a 32-entry LDS map (each frame covered by exactly one t; frames
//     >= total stay -1).
//  3. Streaming gather identical to round 3's winner: branchless clamp to
//     row 0, plain (write-back) stores -- the A/B'd fastest store path.
__global__ __launch_bounds__(256) void lr_fused_kernel(const f4* __restrict__ x,
                                                       const int* __restrict__ dur,
                                                       f4* __restrict__ out,
                                                       float* __restrict__ mel_out) {
    __shared__ int wsum[4];
    __shared__ int im[FPB_];
    const int tid = threadIdx.x;
    // bijective XCD swizzle: 4096 blocks, 8 XCDs, 512 chunks each
    // -> each XCD owns 4 whole batches (4 MB of x) for L2 locality.
    const int bid = ((blockIdx.x & 7) << 9) + (blockIdx.x >> 3);
    const int b  = bid >> 7;                 // batch (128 chunks per batch)
    const int f0 = (bid & 127) * FPB_;       // first frame (local to batch)

    // ---- stage 1: scan ----
    const int2 d2 = ((const int2*)(dur + b * T_))[tid];   // positions 2t, 2t+1
    const int dsum = d2.x + d2.y;
    const int lane = tid & 63;
    const int wave = tid >> 6;
    int v = dsum;                            // inclusive scan of pair-sums
    #pragma unroll
    for (int off = 1; off < 64; off <<= 1) {
        int u = __shfl_up(v, off, 64);
        if (lane >= off) v += u;
    }
    if (lane == 63) wsum[wave] = v;
    if (tid < FPB_) im[tid] = -1;
    __syncthreads();
    int woff = 0, total = 0;
    #pragma unroll
    for (int w = 0; w < 4; ++w) {            // LDS broadcast, conflict-free
        const int s = wsum[w];
        woff  += (w < wave) ? s : 0;
        total += s;
    }
    const int excl = woff + v - dsum;        // exclusive prefix before 2t

    // ---- stage 2: scatter coverage into this block's window ----
    const int f1 = f0 + FPB_;
    {   // position 2t covers [excl, excl+d2.x)
        const int s0 = excl, e0 = excl + d2.x;
        const int lo = s0 > f0 ? s0 : f0, hi = e0 < f1 ? e0 : f1;
        for (int p = lo; p < hi; ++p) im[p - f0] = 2 * tid;
        // position 2t+1 covers [e0, e0+d2.y)
        const int e1 = e0 + d2.y;
        const int lo1 = e0 > f0 ? e0 : f0, hi1 = e1 < f1 ? e1 : f1;
        for (int p = lo1; p < hi1; ++p) im[p - f0] = 2 * tid + 1;
    }
    if ((bid & 127) == 0 && tid == 0)
        mel_out[b] = (float)(total > 1 ? total : 1);
    __syncthreads();

    // ---- stage 3: streaming gather (32 frames, 16 f4 stores/thread) ----
    const f4* __restrict__ xb = x + ((size_t)(b * T_) << 7);
    const int c = tid & 127;                 // f4 column within frame
    const size_t base = (((size_t)b * MAXF_ + f0) << 7) + tid;
    #pragma unroll
    for (int k = 0; k < 16; ++k) {
        const int fl = (tid >> 7) + 2 * k;   // local frame 0..31
        const int idx = im[fl];              // wave-uniform LDS broadcast
        const int cidx = idx < 0 ? 0 : idx;  // clamp: masked -> row 0 (hot)
        f4 vv = xb[((size_t)cidx << 7) + c];
        if (idx < 0) vv = (f4){0.f, 0.f, 0.f, 0.f};  // v_cndmask, no branch
        out[base + (size_t)k * 256] = vv;    // plain store (won round-3 A/B)
    }
}

extern "C" void kernel_launch(void* const* d_in, const int* in_sizes, int n_in,
                              void* d_out, int out_size, void* d_ws, size_t ws_size,
                              hipStream_t stream) {
    const float* x = (const float*)d_in[0];
    const int* durations = (const int*)d_in[1];
    float* out = (float*)d_out;
    float* mel_out = out + (size_t)B_ * MAXF_ * D_;
    (void)d_ws; (void)ws_size;

    lr_fused_kernel<<<NBLK_, 256, 0, stream>>>(
        (const f4*)x, durations, (f4*)out, mel_out);
}